// Round 10
// baseline (1963.736 us; speedup 1.0000x reference)
//
#include <hip/hip_runtime.h>

// DCRNN (DCE'd): 65536 independent sequences, 12 steps, 2-layer GRU-lite, H=64.
// fp32 vector-ALU implementation (no fp32 MFMA on CDNA4).
//
// Round-10: merged-phase pipeline, designed INTO the empirical 64-VGPR cap.
//   Phase p (p=0..12) computes L1(t=p-1) AND L0(t=p) from one A snapshot:
//     z1 = b1 + [h0(p-1) | h1(p-2)] @ W1      (store h1(p-1) if p>=1)
//     z0 = b0 + x(p) @ W0x + h0(p-1) @ W0h    (store h0(p)   if p<12)
//   For k<64 ONE h float2 read feeds both matmuls (32 FMAs/ds_read).
//   1024 thr (16 waves) x 128 seqs; wave owns 4 cols x 2 gates x 2 layers
//   (32 named accumulators); lane owns 2 seqs. Weights single-buffered via
//   VMEM broadcast (w NOT readfirstlane'd -> no SMEM/lgkmcnt mixing).
//   2 barriers/phase. LDS 64KB -> 2 blocks/CU -> 32 waves/CU = 8/SIMD.

#define TSTEPS 12

__device__ __forceinline__ float fsig(float z) {
    z = fminf(fmaxf(z, -30.f), 30.f);
    return 1.f / (1.f + __expf(-z));
}
__device__ __forceinline__ float ftanh(float z) {
    z = fminf(fmaxf(z, -15.f), 15.f);
    float e = __expf(2.f * z);
    return 1.f - 2.f / (e + 1.f);
}

// ---- workspace layout (floats) ----
// [0, 16384)      M0 : [k(64)][w(16)][16]  j0-3: Wu0[2+k][w*4+j], j4-7: Wc0,
//                                          j8-11: Wu1[k][...], j12-15: Wc1
// [16384, 24576)  M1 : [k(64)][w(16)][8]   j0-3: Wu1[64+k], j4-7: Wc1[64+k]
// [24576, 24832)  X  : [k(2)][w(16)][8]    rows 0..1 of Wu0/Wc0
// [24832, 24960)  B0 : [w(16)][8]  bu0|bc0 cols w*4..
// [24960, 25088)  B1 : [w(16)][8]  bu1|bc1

__global__ void pack_weights(const float* __restrict__ Wu0, const float* __restrict__ bu0,
                             const float* __restrict__ Wc0, const float* __restrict__ bc0,
                             const float* __restrict__ Wu1, const float* __restrict__ bu1,
                             const float* __restrict__ Wc1, const float* __restrict__ bc1,
                             float* __restrict__ Wp) {
    const int tid = blockIdx.x * blockDim.x + threadIdx.x;
    const int nthr = gridDim.x * blockDim.x;
    for (int i = tid; i < 16384; i += nthr) {
        const int k = i >> 8, r = i & 255, wv = r >> 4, j = r & 15;
        const int col = wv * 4 + (j & 3);
        float v;
        if (j < 4)       v = Wu0[(2 + k) * 64 + col];
        else if (j < 8)  v = Wc0[(2 + k) * 64 + col];
        else if (j < 12) v = Wu1[k * 64 + col];
        else             v = Wc1[k * 64 + col];
        Wp[i] = v;
    }
    for (int i = tid; i < 8192; i += nthr) {
        const int k = i >> 7, r = i & 127, wv = r >> 3, j = r & 7;
        const int col = wv * 4 + (j & 3);
        Wp[16384 + i] = (j < 4) ? Wu1[(64 + k) * 64 + col] : Wc1[(64 + k) * 64 + col];
    }
    for (int i = tid; i < 256; i += nthr) {
        const int k = i >> 7, r = i & 127, wv = r >> 3, j = r & 7;
        const int col = wv * 4 + (j & 3);
        Wp[24576 + i] = (j < 4) ? Wu0[k * 64 + col] : Wc0[k * 64 + col];
    }
    for (int i = tid; i < 128; i += nthr) {
        const int wv = i >> 3, j = i & 7;
        const int col = wv * 4 + (j & 3);
        Wp[24832 + i] = (j < 4) ? bu0[col] : bc0[col];
        Wp[24960 + i] = (j < 4) ? bu1[col] : bc1[col];
    }
}

// ---- macro machinery: named regs only ----
#define F(a, b, c) __builtin_fmaf((a), (b), (c))

// 8 FMAs: 4 cols (W.xyzw) x 2 seqs (HV.x/.y) into U0..U3 (suffix 0/1)
#define FMA8(U0, U1, U2, U3, HV, W) \
    U0##0 = F(HV.x, W.x, U0##0); U0##1 = F(HV.y, W.x, U0##1); \
    U1##0 = F(HV.x, W.y, U1##0); U1##1 = F(HV.y, W.y, U1##1); \
    U2##0 = F(HV.x, W.z, U2##0); U2##1 = F(HV.y, W.z, U2##1); \
    U3##0 = F(HV.x, W.w, U3##0); U3##1 = F(HV.y, W.w, U3##1);

#define KLO(KK) { \
    const float2 hv = *(const float2*)(Ab + (KK) * 128); \
    const float4 q0 = WLo[(KK) * 64 + 0], q1 = WLo[(KK) * 64 + 1]; \
    FMA8(aU0, aU1, aU2, aU3, hv, q0) \
    FMA8(aC0, aC1, aC2, aC3, hv, q1) \
    const float4 q2 = WLo[(KK) * 64 + 2], q3 = WLo[(KK) * 64 + 3]; \
    FMA8(bU0, bU1, bU2, bU3, hv, q2) \
    FMA8(bC0, bC1, bC2, bC3, hv, q3) }

#define KHI(KK) { \
    const float2 hv = *(const float2*)(Ab + (64 + (KK)) * 128); \
    const float4 q2 = WHi[(KK) * 32 + 0], q3 = WHi[(KK) * 32 + 1]; \
    FMA8(bU0, bU1, bU2, bU3, hv, q2) \
    FMA8(bC0, bC1, bC2, bC3, hv, q3) }

#define ZSET(A0, A1, A2, A3, V) A0##0 = V.x; A0##1 = V.x; A1##0 = V.y; A1##1 = V.y; \
                                A2##0 = V.z; A2##1 = V.z; A3##0 = V.w; A3##1 = V.w;

#define ACT0(J) { \
    const float2 ho = *(const float2*)(A + (w4 + (J)) * 128 + 2 * lane); \
    float u_, c_; \
    u_ = fsig(aU##J##0); c_ = ftanh(aC##J##0); hn0_##J.x = F(u_, ho.x, (1.f - u_) * c_); \
    u_ = fsig(aU##J##1); c_ = ftanh(aC##J##1); hn0_##J.y = F(u_, ho.y, (1.f - u_) * c_); }

#define ACT1(J) { \
    const float2 ho = *(const float2*)(A + (64 + w4 + (J)) * 128 + 2 * lane); \
    float u_, c_; \
    u_ = fsig(bU##J##0); c_ = ftanh(bC##J##0); hn1_##J.x = F(u_, ho.x, (1.f - u_) * c_); \
    u_ = fsig(bU##J##1); c_ = ftanh(bC##J##1); hn1_##J.y = F(u_, ho.y, (1.f - u_) * c_); }

__global__ __launch_bounds__(1024, 8) void dcrnn_main(const float* __restrict__ x,
                                                      const float* __restrict__ Wp,
                                                      const float* __restrict__ Wo,
                                                      const float* __restrict__ bo,
                                                      float* __restrict__ out) {
    __shared__ float A[128 * 128];  // A[k][seq]: rows 0..63 h0, 64..127 h1

    const int tid = threadIdx.x;
    const int lane = tid & 63;
    const int w = tid >> 6;   // 0..15; NOT readfirstlane'd -> weight loads stay VMEM
    const int w4 = w * 4;

    const int s0 = blockIdx.x * 128;
    const int b = s0 >> 11;
    const int n0 = s0 & 2047;

    const float4* WLo = (const float4*)Wp + w * 4;              // M0 [k][w][16]
    const float4* WHi = (const float4*)(Wp + 16384) + w * 2;    // M1 [k][w][8]
    const float4* WX  = (const float4*)(Wp + 24576) + w * 2;    // X  [k][w][8]
    const float4* B0p = (const float4*)(Wp + 24832) + w * 2;
    const float4* B1p = (const float4*)(Wp + 24960) + w * 2;

    for (int i = tid; i < 128 * 128; i += 1024) A[i] = 0.f;
    __syncthreads();

    const float* Ab = A + 2 * lane;
    const float* xlane = x + (size_t)b * (TSTEPS * 4096) + (size_t)(n0 + 2 * lane) * 2;

    float aU00, aU01, aU10, aU11, aU20, aU21, aU30, aU31;  // L0 u-gate
    float aC00, aC01, aC10, aC11, aC20, aC21, aC30, aC31;  // L0 c-gate
    float bU00, bU01, bU10, bU11, bU20, bU21, bU30, bU31;  // L1 u-gate
    float bC00, bC01, bC10, bC11, bC20, bC21, bC30, bC31;  // L1 c-gate
    float2 hn0_0, hn0_1, hn0_2, hn0_3;
    float2 hn1_0, hn1_1, hn1_2, hn1_3;

#pragma unroll 1
    for (int p = 0; p < TSTEPS + 1; ++p) {
        const int xt = (p < TSTEPS) ? p : (TSTEPS - 1);  // p=12 compute is discarded

        {
            const float4 v0 = B0p[0], v1 = B0p[1];
            ZSET(aU0, aU1, aU2, aU3, v0)
            ZSET(aC0, aC1, aC2, aC3, v1)
            const float4 v2 = B1p[0], v3 = B1p[1];
            ZSET(bU0, bU1, bU2, bU3, v2)
            ZSET(bC0, bC1, bC2, bC3, v3)
        }

        // ---- shared-k range: h0(p-1) feeds BOTH layers ----
#pragma unroll 4
        for (int k = 0; k < 64; ++k) { KLO(k) }

        // ---- x part of layer 0 ----
        {
            const float4 xv = *(const float4*)(xlane + (size_t)xt * 4096);
            const float4 q0 = WX[0], q1 = WX[1];    // k=0 (d0)
            const float4 q2 = WX[32], q3 = WX[33];  // k=1 (d1)
            const float2 x0 = make_float2(xv.x, xv.z);
            const float2 x1 = make_float2(xv.y, xv.w);
            FMA8(aU0, aU1, aU2, aU3, x0, q0)
            FMA8(aC0, aC1, aC2, aC3, x0, q1)
            FMA8(aU0, aU1, aU2, aU3, x1, q2)
            FMA8(aC0, aC1, aC2, aC3, x1, q3)
        }
        ACT0(0) ACT0(1) ACT0(2) ACT0(3)   // retire z0 -> hn0 (frees 16 accs)

        // ---- h1(p-2) range: layer 1 only ----
#pragma unroll 4
        for (int k = 0; k < 64; ++k) { KHI(k) }
        ACT1(0) ACT1(1) ACT1(2) ACT1(3)

        __syncthreads();  // (1) all reads of the A snapshot done
        if (p < TSTEPS) {
            *(float2*)(A + (w4 + 0) * 128 + 2 * lane) = hn0_0;
            *(float2*)(A + (w4 + 1) * 128 + 2 * lane) = hn0_1;
            *(float2*)(A + (w4 + 2) * 128 + 2 * lane) = hn0_2;
            *(float2*)(A + (w4 + 3) * 128 + 2 * lane) = hn0_3;
        }
        if (p >= 1) {
            *(float2*)(A + (64 + w4 + 0) * 128 + 2 * lane) = hn1_0;
            *(float2*)(A + (64 + w4 + 1) * 128 + 2 * lane) = hn1_1;
            *(float2*)(A + (64 + w4 + 2) * 128 + 2 * lane) = hn1_2;
            *(float2*)(A + (64 + w4 + 3) * 128 + 2 * lane) = hn1_3;
        }
        __syncthreads();  // (2) new state visible
    }

    // ---- epilogue: out = h1(11) @ Wo + bo ; h1 final in A rows 64..127 ----
    if (tid < 128) {
        float acc = bo[0];
#pragma unroll 8
        for (int k = 0; k < 64; ++k)
            acc = F(A[(64 + k) * 128 + tid], Wo[k], acc);
        out[s0 + tid] = acc;
    }
}

extern "C" void kernel_launch(void* const* d_in, const int* in_sizes, int n_in,
                              void* d_out, int out_size, void* d_ws, size_t ws_size,
                              hipStream_t stream) {
    const float* x   = (const float*)d_in[0];
    // d_in[1] supports, d_in[2] Wr0, d_in[3] br0 : dead code in reference
    const float* Wu0 = (const float*)d_in[4];
    const float* bu0 = (const float*)d_in[5];
    const float* Wc0 = (const float*)d_in[6];
    const float* bc0 = (const float*)d_in[7];
    // d_in[8] Wd0, d_in[9] bd0, d_in[10] Wr1, d_in[11] br1 : dead
    const float* Wu1 = (const float*)d_in[12];
    const float* bu1 = (const float*)d_in[13];
    const float* Wc1 = (const float*)d_in[14];
    const float* bc1 = (const float*)d_in[15];
    // d_in[16] Wd1, d_in[17] bd1 : dead
    const float* Wo  = (const float*)d_in[18];
    const float* bo  = (const float*)d_in[19];

    float* Wp = (float*)d_ws;  // ~100 KB

    hipLaunchKernelGGL(pack_weights, dim3(64), dim3(256), 0, stream,
                       Wu0, bu0, Wc0, bc0, Wu1, bu1, Wc1, bc1, Wp);
    hipLaunchKernelGGL(dcrnn_main, dim3(65536 / 128), dim3(1024), 0, stream,
                       x, Wp, Wo, bo, (float*)d_out);
}

// Round 13
// 1328.179 us; speedup vs baseline: 1.4785x; 1.4785x over previous
//
#include <hip/hip_runtime.h>

// DCRNN (DCE'd): 65536 independent sequences, 12 steps, 2-layer GRU-lite, H=64.
// fp32 vector-ALU implementation (no fp32 MFMA on CDNA4).
//
// Round-11: round-10 merged-phase pipeline with the launch-bounds fix.
//   r10's __launch_bounds__(1024,8) squeezed the allocator to 32 VGPRs ->
//   800MB of accumulator spill traffic per dispatch. Series: (512,4)->64,
//   (1024,8)->32: the 2nd arg acts like a min-BLOCKS multiplier here. Fix:
//   plain __launch_bounds__(1024); LDS (64KB) caps residency at 2 blocks/CU
//   = 8 waves/SIMD and the un-hinted allocator lands at 64 VGPRs (r2-r8).
//   Also unroll 4->2 on the k-loops to bound weight-load hoisting pressure.
//
//   Phase p (p=0..12) computes L1(t=p-1) AND L0(t=p) from one A snapshot:
//     z1 = b1 + [h0(p-1) | h1(p-2)] @ W1      (store h1(p-1) if p>=1)
//     z0 = b0 + x(p) @ W0x + h0(p-1) @ W0h    (store h0(p)   if p<12)
//   For k<64 ONE h float2 read feeds both matmuls (32 FMAs/ds_read).
//   1024 thr (16 waves) x 128 seqs; wave owns 4 cols x 2 gates x 2 layers
//   (32 named accumulators); lane owns 2 seqs. Weights single-buffered via
//   VMEM broadcast (w NOT readfirstlane'd). 2 barriers/phase.

#define TSTEPS 12

__device__ __forceinline__ float fsig(float z) {
    z = fminf(fmaxf(z, -30.f), 30.f);
    return 1.f / (1.f + __expf(-z));
}
__device__ __forceinline__ float ftanh(float z) {
    z = fminf(fmaxf(z, -15.f), 15.f);
    float e = __expf(2.f * z);
    return 1.f - 2.f / (e + 1.f);
}

// ---- workspace layout (floats) ----
// [0, 16384)      M0 : [k(64)][w(16)][16]  j0-3: Wu0[2+k][w*4+j], j4-7: Wc0,
//                                          j8-11: Wu1[k][...], j12-15: Wc1
// [16384, 24576)  M1 : [k(64)][w(16)][8]   j0-3: Wu1[64+k], j4-7: Wc1[64+k]
// [24576, 24832)  X  : [k(2)][w(16)][8]    rows 0..1 of Wu0/Wc0
// [24832, 24960)  B0 : [w(16)][8]  bu0|bc0 cols w*4..
// [24960, 25088)  B1 : [w(16)][8]  bu1|bc1

__global__ void pack_weights(const float* __restrict__ Wu0, const float* __restrict__ bu0,
                             const float* __restrict__ Wc0, const float* __restrict__ bc0,
                             const float* __restrict__ Wu1, const float* __restrict__ bu1,
                             const float* __restrict__ Wc1, const float* __restrict__ bc1,
                             float* __restrict__ Wp) {
    const int tid = blockIdx.x * blockDim.x + threadIdx.x;
    const int nthr = gridDim.x * blockDim.x;
    for (int i = tid; i < 16384; i += nthr) {
        const int k = i >> 8, r = i & 255, wv = r >> 4, j = r & 15;
        const int col = wv * 4 + (j & 3);
        float v;
        if (j < 4)       v = Wu0[(2 + k) * 64 + col];
        else if (j < 8)  v = Wc0[(2 + k) * 64 + col];
        else if (j < 12) v = Wu1[k * 64 + col];
        else             v = Wc1[k * 64 + col];
        Wp[i] = v;
    }
    for (int i = tid; i < 8192; i += nthr) {
        const int k = i >> 7, r = i & 127, wv = r >> 3, j = r & 7;
        const int col = wv * 4 + (j & 3);
        Wp[16384 + i] = (j < 4) ? Wu1[(64 + k) * 64 + col] : Wc1[(64 + k) * 64 + col];
    }
    for (int i = tid; i < 256; i += nthr) {
        const int k = i >> 7, r = i & 127, wv = r >> 3, j = r & 7;
        const int col = wv * 4 + (j & 3);
        Wp[24576 + i] = (j < 4) ? Wu0[k * 64 + col] : Wc0[k * 64 + col];
    }
    for (int i = tid; i < 128; i += nthr) {
        const int wv = i >> 3, j = i & 7;
        const int col = wv * 4 + (j & 3);
        Wp[24832 + i] = (j < 4) ? bu0[col] : bc0[col];
        Wp[24960 + i] = (j < 4) ? bu1[col] : bc1[col];
    }
}

// ---- macro machinery: named regs only ----
#define F(a, b, c) __builtin_fmaf((a), (b), (c))

// 8 FMAs: 4 cols (W.xyzw) x 2 seqs (HV.x/.y) into U0..U3 (suffix 0/1)
#define FMA8(U0, U1, U2, U3, HV, W) \
    U0##0 = F(HV.x, W.x, U0##0); U0##1 = F(HV.y, W.x, U0##1); \
    U1##0 = F(HV.x, W.y, U1##0); U1##1 = F(HV.y, W.y, U1##1); \
    U2##0 = F(HV.x, W.z, U2##0); U2##1 = F(HV.y, W.z, U2##1); \
    U3##0 = F(HV.x, W.w, U3##0); U3##1 = F(HV.y, W.w, U3##1);

#define KLO(KK) { \
    const float2 hv = *(const float2*)(Ab + (KK) * 128); \
    const float4 q0 = WLo[(KK) * 64 + 0], q1 = WLo[(KK) * 64 + 1]; \
    FMA8(aU0, aU1, aU2, aU3, hv, q0) \
    FMA8(aC0, aC1, aC2, aC3, hv, q1) \
    const float4 q2 = WLo[(KK) * 64 + 2], q3 = WLo[(KK) * 64 + 3]; \
    FMA8(bU0, bU1, bU2, bU3, hv, q2) \
    FMA8(bC0, bC1, bC2, bC3, hv, q3) }

#define KHI(KK) { \
    const float2 hv = *(const float2*)(Ab + (64 + (KK)) * 128); \
    const float4 q2 = WHi[(KK) * 32 + 0], q3 = WHi[(KK) * 32 + 1]; \
    FMA8(bU0, bU1, bU2, bU3, hv, q2) \
    FMA8(bC0, bC1, bC2, bC3, hv, q3) }

#define ZSET(A0, A1, A2, A3, V) A0##0 = V.x; A0##1 = V.x; A1##0 = V.y; A1##1 = V.y; \
                                A2##0 = V.z; A2##1 = V.z; A3##0 = V.w; A3##1 = V.w;

#define ACT0(J) { \
    const float2 ho = *(const float2*)(A + (w4 + (J)) * 128 + 2 * lane); \
    float u_, c_; \
    u_ = fsig(aU##J##0); c_ = ftanh(aC##J##0); hn0_##J.x = F(u_, ho.x, (1.f - u_) * c_); \
    u_ = fsig(aU##J##1); c_ = ftanh(aC##J##1); hn0_##J.y = F(u_, ho.y, (1.f - u_) * c_); }

#define ACT1(J) { \
    const float2 ho = *(const float2*)(A + (64 + w4 + (J)) * 128 + 2 * lane); \
    float u_, c_; \
    u_ = fsig(bU##J##0); c_ = ftanh(bC##J##0); hn1_##J.x = F(u_, ho.x, (1.f - u_) * c_); \
    u_ = fsig(bU##J##1); c_ = ftanh(bC##J##1); hn1_##J.y = F(u_, ho.y, (1.f - u_) * c_); }

__global__ __launch_bounds__(1024) void dcrnn_main(const float* __restrict__ x,
                                                   const float* __restrict__ Wp,
                                                   const float* __restrict__ Wo,
                                                   const float* __restrict__ bo,
                                                   float* __restrict__ out) {
    __shared__ float A[128 * 128];  // A[k][seq]: rows 0..63 h0, 64..127 h1

    const int tid = threadIdx.x;
    const int lane = tid & 63;
    const int w = tid >> 6;   // 0..15; NOT readfirstlane'd -> weight loads stay VMEM
    const int w4 = w * 4;

    const int s0 = blockIdx.x * 128;
    const int b = s0 >> 11;
    const int n0 = s0 & 2047;

    const float4* WLo = (const float4*)Wp + w * 4;              // M0 [k][w][16]
    const float4* WHi = (const float4*)(Wp + 16384) + w * 2;    // M1 [k][w][8]
    const float4* WX  = (const float4*)(Wp + 24576) + w * 2;    // X  [k][w][8]
    const float4* B0p = (const float4*)(Wp + 24832) + w * 2;
    const float4* B1p = (const float4*)(Wp + 24960) + w * 2;

    for (int i = tid; i < 128 * 128; i += 1024) A[i] = 0.f;
    __syncthreads();

    const float* Ab = A + 2 * lane;
    const float* xlane = x + (size_t)b * (TSTEPS * 4096) + (size_t)(n0 + 2 * lane) * 2;

    float aU00, aU01, aU10, aU11, aU20, aU21, aU30, aU31;  // L0 u-gate
    float aC00, aC01, aC10, aC11, aC20, aC21, aC30, aC31;  // L0 c-gate
    float bU00, bU01, bU10, bU11, bU20, bU21, bU30, bU31;  // L1 u-gate
    float bC00, bC01, bC10, bC11, bC20, bC21, bC30, bC31;  // L1 c-gate
    float2 hn0_0, hn0_1, hn0_2, hn0_3;
    float2 hn1_0, hn1_1, hn1_2, hn1_3;

#pragma unroll 1
    for (int p = 0; p < TSTEPS + 1; ++p) {
        const int xt = (p < TSTEPS) ? p : (TSTEPS - 1);  // p=12 compute is discarded

        {
            const float4 v0 = B0p[0], v1 = B0p[1];
            ZSET(aU0, aU1, aU2, aU3, v0)
            ZSET(aC0, aC1, aC2, aC3, v1)
            const float4 v2 = B1p[0], v3 = B1p[1];
            ZSET(bU0, bU1, bU2, bU3, v2)
            ZSET(bC0, bC1, bC2, bC3, v3)
        }

        // ---- shared-k range: h0(p-1) feeds BOTH layers ----
#pragma unroll 2
        for (int k = 0; k < 64; ++k) { KLO(k) }

        // ---- x part of layer 0 ----
        {
            const float4 xv = *(const float4*)(xlane + (size_t)xt * 4096);
            const float4 q0 = WX[0], q1 = WX[1];    // k=0 (d0)
            const float4 q2 = WX[32], q3 = WX[33];  // k=1 (d1)
            const float2 x0 = make_float2(xv.x, xv.z);
            const float2 x1 = make_float2(xv.y, xv.w);
            FMA8(aU0, aU1, aU2, aU3, x0, q0)
            FMA8(aC0, aC1, aC2, aC3, x0, q1)
            FMA8(aU0, aU1, aU2, aU3, x1, q2)
            FMA8(aC0, aC1, aC2, aC3, x1, q3)
        }
        ACT0(0) ACT0(1) ACT0(2) ACT0(3)   // retire z0 -> hn0 (frees 16 accs)

        // ---- h1(p-2) range: layer 1 only ----
#pragma unroll 2
        for (int k = 0; k < 64; ++k) { KHI(k) }
        ACT1(0) ACT1(1) ACT1(2) ACT1(3)

        __syncthreads();  // (1) all reads of the A snapshot done
        if (p < TSTEPS) {
            *(float2*)(A + (w4 + 0) * 128 + 2 * lane) = hn0_0;
            *(float2*)(A + (w4 + 1) * 128 + 2 * lane) = hn0_1;
            *(float2*)(A + (w4 + 2) * 128 + 2 * lane) = hn0_2;
            *(float2*)(A + (w4 + 3) * 128 + 2 * lane) = hn0_3;
        }
        if (p >= 1) {
            *(float2*)(A + (64 + w4 + 0) * 128 + 2 * lane) = hn1_0;
            *(float2*)(A + (64 + w4 + 1) * 128 + 2 * lane) = hn1_1;
            *(float2*)(A + (64 + w4 + 2) * 128 + 2 * lane) = hn1_2;
            *(float2*)(A + (64 + w4 + 3) * 128 + 2 * lane) = hn1_3;
        }
        __syncthreads();  // (2) new state visible
    }

    // ---- epilogue: out = h1(11) @ Wo + bo ; h1 final in A rows 64..127 ----
    if (tid < 128) {
        float acc = bo[0];
#pragma unroll 8
        for (int k = 0; k < 64; ++k)
            acc = F(A[(64 + k) * 128 + tid], Wo[k], acc);
        out[s0 + tid] = acc;
    }
}

extern "C" void kernel_launch(void* const* d_in, const int* in_sizes, int n_in,
                              void* d_out, int out_size, void* d_ws, size_t ws_size,
                              hipStream_t stream) {
    const float* x   = (const float*)d_in[0];
    // d_in[1] supports, d_in[2] Wr0, d_in[3] br0 : dead code in reference
    const float* Wu0 = (const float*)d_in[4];
    const float* bu0 = (const float*)d_in[5];
    const float* Wc0 = (const float*)d_in[6];
    const float* bc0 = (const float*)d_in[7];
    // d_in[8] Wd0, d_in[9] bd0, d_in[10] Wr1, d_in[11] br1 : dead
    const float* Wu1 = (const float*)d_in[12];
    const float* bu1 = (const float*)d_in[13];
    const float* Wc1 = (const float*)d_in[14];
    const float* bc1 = (const float*)d_in[15];
    // d_in[16] Wd1, d_in[17] bd1 : dead
    const float* Wo  = (const float*)d_in[18];
    const float* bo  = (const float*)d_in[19];

    float* Wp = (float*)d_ws;  // ~100 KB

    hipLaunchKernelGGL(pack_weights, dim3(64), dim3(256), 0, stream,
                       Wu0, bu0, Wc0, bc0, Wu1, bu1, Wc1, bc1, Wp);
    hipLaunchKernelGGL(dcrnn_main, dim3(65536 / 128), dim3(1024), 0, stream,
                       x, Wp, Wo, bo, (float*)d_out);
}

// Round 14
// 1029.556 us; speedup vs baseline: 1.9074x; 1.2900x over previous
//
#include <hip/hip_runtime.h>

// DCRNN (DCE'd): 65536 independent sequences, 12 steps, 2-layer GRU-lite, H=64.
// fp32 vector-ALU implementation (no fp32 MFMA on CDNA4).
//
// Round-14: REGISTER-RESIDENT WEIGHTS + v_readlane broadcast.
//   r8/r9/r13 all died on the same wall: weights streamed per-k-step through
//   a 64-VGPR file (s_load -> lgkmcnt drains; VMEM dbuf -> spills; shallow
//   VMEM -> 300cyc latency uncoverable). Fix: lane l holds the k=l weight
//   slice permanently (24 VGPRs/lane total); inner loop broadcasts them with
//   v_readlane (dest SGPR, FMA reads it directly). Hot loop = 8 readlane +
//   1 ds_read_b64 + 16 FMA per k-step: NO VMEM, NO SMEM, ds_read trivially
//   pipelined on in-order lgkmcnt. VALU-bound @ ~369us ideal.
//   Geometry: 1024 thr (16 waves) x 128 seqs; lane = 2 seqs; wave owns 4
//   cols x {u,c}; un-merged L0/L1 (3 barriers/step) -> peak ~56 VGPR live.

#define TSTEPS 12

__device__ __forceinline__ float fsig(float z) {
    z = fminf(fmaxf(z, -30.f), 30.f);
    return 1.f / (1.f + __expf(-z));
}
__device__ __forceinline__ float ftanh(float z) {
    z = fminf(fmaxf(z, -15.f), 15.f);
    float e = __expf(2.f * z);
    return 1.f - 2.f / (e + 1.f);
}

// ---- workspace layout (floats) ----
// [0, 8192)       L0h [k(64)][w(16)][8]   j<4: Wu0[2+k][w*4+j], j>=4: Wc0[2+k][w*4+j-4]
// [8192, 24576)   L1h [k(128)][w(16)][8]  j<4: Wu1[k][w*4+j],   j>=4: Wc1
// [24576, 24832)  X   [k(2)][w(16)][8]    rows 0..1 of Wu0/Wc0
// [24832, 24960)  B0  [w(16)][8]   bu0|bc0, cols w*4..w*4+3
// [24960, 25088)  B1  [w(16)][8]   bu1|bc1

__global__ void pack_weights(const float* __restrict__ Wu0, const float* __restrict__ bu0,
                             const float* __restrict__ Wc0, const float* __restrict__ bc0,
                             const float* __restrict__ Wu1, const float* __restrict__ bu1,
                             const float* __restrict__ Wc1, const float* __restrict__ bc1,
                             float* __restrict__ Wp) {
    const int tid = blockIdx.x * blockDim.x + threadIdx.x;
    const int nthr = gridDim.x * blockDim.x;
    for (int i = tid; i < 8192; i += nthr) {
        const int k = i >> 7, r = i & 127, wv = r >> 3, j = r & 7;
        const int col = wv * 4 + (j & 3);
        Wp[i] = (j < 4) ? Wu0[(2 + k) * 64 + col] : Wc0[(2 + k) * 64 + col];
    }
    for (int i = tid; i < 16384; i += nthr) {
        const int k = i >> 7, r = i & 127, wv = r >> 3, j = r & 7;
        const int col = wv * 4 + (j & 3);
        Wp[8192 + i] = (j < 4) ? Wu1[k * 64 + col] : Wc1[k * 64 + col];
    }
    for (int i = tid; i < 256; i += nthr) {
        const int k = i >> 7, r = i & 127, wv = r >> 3, j = r & 7;
        const int col = wv * 4 + (j & 3);
        Wp[24576 + i] = (j < 4) ? Wu0[k * 64 + col] : Wc0[k * 64 + col];
    }
    for (int i = tid; i < 128; i += nthr) {
        const int wv = i >> 3, j = i & 7;
        const int col = wv * 4 + (j & 3);
        Wp[24832 + i] = (j < 4) ? bu0[col] : bc0[col];
        Wp[24960 + i] = (j < 4) ? bu1[col] : bc1[col];
    }
}

// ---- macro machinery: named regs only ----
#define F(a, b, c) __builtin_fmaf((a), (b), (c))
#define RL(v, K) __int_as_float(__builtin_amdgcn_readlane(__float_as_int(v), (K)))

// one k-step: broadcast 8 weights from lane KK, read h float2 at ROW, 16 FMAs
#define KSTEP(WU, WC, KK, ROW) { \
    const float2 hv = *(const float2*)(Ab + (ROW) * 128); \
    const float su0 = RL(WU.x, (KK)), su1 = RL(WU.y, (KK)); \
    const float su2 = RL(WU.z, (KK)), su3 = RL(WU.w, (KK)); \
    const float sc0 = RL(WC.x, (KK)), sc1 = RL(WC.y, (KK)); \
    const float sc2 = RL(WC.z, (KK)), sc3 = RL(WC.w, (KK)); \
    zu00 = F(hv.x, su0, zu00); zu01 = F(hv.y, su0, zu01); \
    zu10 = F(hv.x, su1, zu10); zu11 = F(hv.y, su1, zu11); \
    zu20 = F(hv.x, su2, zu20); zu21 = F(hv.y, su2, zu21); \
    zu30 = F(hv.x, su3, zu30); zu31 = F(hv.y, su3, zu31); \
    zc00 = F(hv.x, sc0, zc00); zc01 = F(hv.y, sc0, zc01); \
    zc10 = F(hv.x, sc1, zc10); zc11 = F(hv.y, sc1, zc11); \
    zc20 = F(hv.x, sc2, zc20); zc21 = F(hv.y, sc2, zc21); \
    zc30 = F(hv.x, sc3, zc30); zc31 = F(hv.y, sc3, zc31); }

#define ZINIT(BU, BC) \
    zu00 = BU.x; zu01 = BU.x; zu10 = BU.y; zu11 = BU.y; \
    zu20 = BU.z; zu21 = BU.z; zu30 = BU.w; zu31 = BU.w; \
    zc00 = BC.x; zc01 = BC.x; zc10 = BC.y; zc11 = BC.y; \
    zc20 = BC.z; zc21 = BC.z; zc30 = BC.w; zc31 = BC.w;

// x contribution for one input feature: XA = x[seq0][d], XB = x[seq1][d]
#define XPART(XA, XB, QU, QC) \
    zu00 = F(XA, QU.x, zu00); zu01 = F(XB, QU.x, zu01); \
    zu10 = F(XA, QU.y, zu10); zu11 = F(XB, QU.y, zu11); \
    zu20 = F(XA, QU.z, zu20); zu21 = F(XB, QU.z, zu21); \
    zu30 = F(XA, QU.w, zu30); zu31 = F(XB, QU.w, zu31); \
    zc00 = F(XA, QC.x, zc00); zc01 = F(XB, QC.x, zc01); \
    zc10 = F(XA, QC.y, zc10); zc11 = F(XB, QC.y, zc11); \
    zc20 = F(XA, QC.z, zc20); zc21 = F(XB, QC.z, zc21); \
    zc30 = F(XA, QC.w, zc30); zc31 = F(XB, QC.w, zc31);

#define ACTJ(J, ROWBASE) { \
    const float2 ho = *(const float2*)(A + ((ROWBASE) + (J)) * 128 + 2 * lane); \
    float u_ = fsig(zu##J##0), c_ = ftanh(zc##J##0); \
    hn##J##0 = F(u_, ho.x, (1.f - u_) * c_); \
    u_ = fsig(zu##J##1); c_ = ftanh(zc##J##1); \
    hn##J##1 = F(u_, ho.y, (1.f - u_) * c_); }

#define STJ(J, ROWBASE) \
    *(float2*)(A + ((ROWBASE) + (J)) * 128 + 2 * lane) = make_float2(hn##J##0, hn##J##1);

__global__ __launch_bounds__(1024) void dcrnn_main(const float* __restrict__ x,
                                                   const float* __restrict__ Wp,
                                                   const float* __restrict__ Wo,
                                                   const float* __restrict__ bo,
                                                   float* __restrict__ out) {
    __shared__ float A[128 * 128];  // A[k][seq]: rows 0..63 h0, 64..127 h1

    const int tid = threadIdx.x;
    const int lane = tid & 63;
    const int w = tid >> 6;     // 0..15
    const int w4 = w * 4;

    const int s0 = blockIdx.x * 128;
    const int b = s0 >> 11;
    const int n0 = s0 & 2047;

    // ---- permanent lane-distributed weights: lane l holds the k=l slice ----
    const float4 wa_u = *(const float4*)(Wp + lane * 128 + w * 8);              // L0h u, k=lane
    const float4 wa_c = *(const float4*)(Wp + lane * 128 + w * 8 + 4);          // L0h c
    const float4 wb_u = *(const float4*)(Wp + 8192 + lane * 128 + w * 8);       // L1h u, k=lane
    const float4 wb_c = *(const float4*)(Wp + 8192 + lane * 128 + w * 8 + 4);
    const float4 wc_u = *(const float4*)(Wp + 8192 + (64 + lane) * 128 + w * 8);  // L1h u, k=64+lane
    const float4 wc_c = *(const float4*)(Wp + 8192 + (64 + lane) * 128 + w * 8 + 4);

    for (int i = tid; i < 128 * 128; i += 1024) A[i] = 0.f;
    __syncthreads();

    const float* Ab = A + 2 * lane;
    const float* xlane = x + (size_t)b * (TSTEPS * 4096) + (size_t)(n0 + 2 * lane) * 2;

    float zu00, zu01, zu10, zu11, zu20, zu21, zu30, zu31;
    float zc00, zc01, zc10, zc11, zc20, zc21, zc30, zc31;
    float hn00, hn01, hn10, hn11, hn20, hn21, hn30, hn31;

#pragma unroll 1
    for (int t = 0; t < TSTEPS; ++t) {
        // ===== layer 0: z0 = b0 + h0_old @ W0h + x @ W0x =====
        {
            const float4 bu = ((const float4*)(Wp + 24832))[w * 2];
            const float4 bc = ((const float4*)(Wp + 24832))[w * 2 + 1];
            ZINIT(bu, bc)
        }
#pragma unroll 4
        for (int kk = 0; kk < 64; ++kk) { KSTEP(wa_u, wa_c, kk, kk) }
        {
            const float4 xv = *(const float4*)(xlane + (size_t)t * 4096);
            const float4 q0 = ((const float4*)(Wp + 24576))[w * 2];
            const float4 q1 = ((const float4*)(Wp + 24576))[w * 2 + 1];
            XPART(xv.x, xv.z, q0, q1)              // input feature d=0
            const float4 q2 = ((const float4*)(Wp + 24576))[32 + w * 2];
            const float4 q3 = ((const float4*)(Wp + 24576))[32 + w * 2 + 1];
            XPART(xv.y, xv.w, q2, q3)              // input feature d=1
        }
        ACTJ(0, w4) ACTJ(1, w4) ACTJ(2, w4) ACTJ(3, w4)
        __syncthreads();  // (1) all reads of h0_old done
        STJ(0, w4) STJ(1, w4) STJ(2, w4) STJ(3, w4)
        __syncthreads();  // (2) h0_new visible

        // ===== layer 1: z1 = b1 + [h0_new | h1_old] @ W1h =====
        {
            const float4 bu = ((const float4*)(Wp + 24960))[w * 2];
            const float4 bc = ((const float4*)(Wp + 24960))[w * 2 + 1];
            ZINIT(bu, bc)
        }
#pragma unroll 4
        for (int kk = 0; kk < 64; ++kk) { KSTEP(wb_u, wb_c, kk, kk) }         // h0_new rows
#pragma unroll 4
        for (int kk = 0; kk < 64; ++kk) { KSTEP(wc_u, wc_c, kk, 64 + kk) }    // h1_old rows
        ACTJ(0, 64 + w4) ACTJ(1, 64 + w4) ACTJ(2, 64 + w4) ACTJ(3, 64 + w4)
        __syncthreads();  // (3) all layer-1 reads done
        STJ(0, 64 + w4) STJ(1, 64 + w4) STJ(2, 64 + w4) STJ(3, 64 + w4)
        // no 4th barrier: next-step L0 touches only rows 0..63 (disjoint);
        // next-step L1 reads of h1 sit behind next step's barriers (1)+(2).
    }

    __syncthreads();  // final h1 visible
    // ===== epilogue: out = h1 @ Wo + bo =====
    if (tid < 128) {
        float acc = bo[0];
#pragma unroll 8
        for (int k = 0; k < 64; ++k)
            acc = F(A[(64 + k) * 128 + tid], Wo[k], acc);
        out[s0 + tid] = acc;
    }
}

extern "C" void kernel_launch(void* const* d_in, const int* in_sizes, int n_in,
                              void* d_out, int out_size, void* d_ws, size_t ws_size,
                              hipStream_t stream) {
    const float* x   = (const float*)d_in[0];
    // d_in[1] supports, d_in[2] Wr0, d_in[3] br0 : dead code in reference
    const float* Wu0 = (const float*)d_in[4];
    const float* bu0 = (const float*)d_in[5];
    const float* Wc0 = (const float*)d_in[6];
    const float* bc0 = (const float*)d_in[7];
    // d_in[8] Wd0, d_in[9] bd0, d_in[10] Wr1, d_in[11] br1 : dead
    const float* Wu1 = (const float*)d_in[12];
    const float* bu1 = (const float*)d_in[13];
    const float* Wc1 = (const float*)d_in[14];
    const float* bc1 = (const float*)d_in[15];
    // d_in[16] Wd1, d_in[17] bd1 : dead
    const float* Wo  = (const float*)d_in[18];
    const float* bo  = (const float*)d_in[19];

    float* Wp = (float*)d_ws;  // ~100 KB

    hipLaunchKernelGGL(pack_weights, dim3(64), dim3(256), 0, stream,
                       Wu0, bu0, Wc0, bc0, Wu1, bu1, Wc1, bc1, Wp);
    hipLaunchKernelGGL(dcrnn_main, dim3(65536 / 128), dim3(1024), 0, stream,
                       x, Wp, Wo, bo, (float*)d_out);
}